// Round 4
// baseline (7704.791 us; speedup 1.0000x reference)
//
#include <hip/hip_runtime.h>
#include <hip/hip_fp16.h>

#define TT   2048
#define EMBD 256
#define HD   256      // H2
#define NG   1024     // 4*H2
#define NC   12
#define NEGV -10000.0f

// recurrence weight split per gate-row: NWv f16 elems in VGPRs, NLv f16 in LDS
#define NWv   192
#define NLv   64
#define LSTRU 34      // LDS row stride in dwords (32 data + 2 pad)

typedef _Float16 half2v __attribute__((ext_vector_type(2)));

// ---- static device scratch (zero dependence on d_ws) ----
__device__ float g_P[2 * TT * NG];   // input-GEMM preactivations (16 MB)
__device__ float g_HS[2 * TT * HD];  // hidden states both dirs (4 MB)
__device__ float g_FE[TT * NC];      // CRF emission feats (96 KB)

// pack two f32 -> two f16 in one dword (one rounding each)
__device__ __forceinline__ unsigned int f2h2(float a, float b) {
  half2v h; h.x = (_Float16)a; h.y = (_Float16)b;
  return __builtin_bit_cast(unsigned int, h);
}
// acc += f32(f16 lo/hi half of w2) * h   -- f32 FMA (VOP3P v_fma_mix_f32)
__device__ __forceinline__ float fmamix_lo(unsigned int w2, float h, float acc) {
  asm("v_fma_mix_f32 %0, %1, %2, %0 op_sel:[0,0,0] op_sel_hi:[1,0,0]"
      : "+v"(acc) : "v"(w2), "v"(h));
  return acc;
}
__device__ __forceinline__ float fmamix_hi(unsigned int w2, float h, float acc) {
  asm("v_fma_mix_f32 %0, %1, %2, %0 op_sel:[1,0,0] op_sel_hi:[1,0,0]"
      : "+v"(acc) : "v"(w2), "v"(h));
  return acc;
}
__device__ __forceinline__ float fsigmoid(float x) { return 1.0f / (1.0f + __expf(-x)); }
__device__ __forceinline__ float ftanh(float x) {
  float a = fabsf(x);
  float e = __expf(-2.0f * a);
  float r = (1.0f - e) / (1.0f + e);
  return copysignf(r, x);
}

// ---------------- K1: embedding gather + input GEMM (+ both biases), all f32 ----------------
__global__ __launch_bounds__(256) void k_input(
    const int* __restrict__ sent, const float* __restrict__ emb,
    const float* __restrict__ WihF, const float* __restrict__ bihF,
    const float* __restrict__ bhhF,
    const float* __restrict__ WihB, const float* __restrict__ bihB,
    const float* __restrict__ bhhB)
{
  const int d  = blockIdx.x & 1;
  const int t0 = (blockIdx.x >> 1) * 16;
  const float* Wih = d ? WihB : WihF;
  const float* bih = d ? bihB : bihF;
  const float* bhh = d ? bhhB : bhhF;
  __shared__ float xs[16][EMBD];
  for (int i = threadIdx.x; i < 16 * (EMBD / 4); i += 256) {
    const int tt = i >> 6, e4 = i & 63;
    reinterpret_cast<float4*>(xs[tt])[e4] =
        reinterpret_cast<const float4*>(emb + (size_t)sent[t0 + tt] * EMBD)[e4];
  }
  __syncthreads();
  for (int gg = 0; gg < 4; ++gg) {
    const int g = threadIdx.x + gg * 256;
    const float bias = bih[g] + bhh[g];
    float acc[16];
#pragma unroll
    for (int tt = 0; tt < 16; ++tt) acc[tt] = 0.0f;
    const float* wr = Wih + (size_t)g * EMBD;
    for (int e = 0; e < EMBD; e += 4) {
      const float4 w = *reinterpret_cast<const float4*>(wr + e);
#pragma unroll
      for (int tt = 0; tt < 16; ++tt) {
        acc[tt] += w.x * xs[tt][e] + w.y * xs[tt][e + 1]
                 + w.z * xs[tt][e + 2] + w.w * xs[tt][e + 3];
      }
    }
    float* Pg = g_P + ((size_t)d * TT + t0) * NG + g;
#pragma unroll
    for (int tt = 0; tt < 16; ++tt) Pg[(size_t)tt * NG] = acc[tt] + bias;
  }
}

// ---------------- K2: BiLSTM recurrence; f16 weights, f32 h/accum; 1 block/direction ----------------
__global__ __launch_bounds__(512, 2) void k_rec(
    const float* __restrict__ WhhF, const float* __restrict__ WhhB,
    const float* __restrict__ h0g, const float* __restrict__ c0g)
{
  __shared__ unsigned int wlu[NG * LSTRU];   // 139264 B: f16x2 weight tails
  __shared__ float hbuf[2 * HD];             // double-buffered f32 h
  __shared__ float aTerm[HD];                // sigmoid(i)*tanh(g)

  const int d = blockIdx.x;
  const float* Whh = d ? WhhB : WhhF;
  const int tid = threadIdx.x;
  const int r0 = tid;            // rows 0..511   = i-gate(0..255), f-gate(0..255)
  const int r1 = tid + 512;      // rows 512..1023 = g-gate, o-gate

  // ---- init: weights f32 -> packed f16 (single rounding) ----
  unsigned int w0[NWv / 2], w1[NWv / 2];
  {
    const float* p0 = Whh + (size_t)r0 * HD;
    const float* p1 = Whh + (size_t)r1 * HD;
#pragma unroll
    for (int j = 0; j < NWv / 2; ++j) {
      const float2 a = *reinterpret_cast<const float2*>(p0 + 2 * j);
      const float2 b = *reinterpret_cast<const float2*>(p1 + 2 * j);
      w0[j] = f2h2(a.x, a.y);
      w1[j] = f2h2(b.x, b.y);
    }
#pragma unroll
    for (int j = 0; j < NLv / 2; ++j) {
      const float2 a = *reinterpret_cast<const float2*>(p0 + NWv + 2 * j);
      const float2 b = *reinterpret_cast<const float2*>(p1 + NWv + 2 * j);
      wlu[r0 * LSTRU + j] = f2h2(a.x, a.y);
      wlu[r1 * LSTRU + j] = f2h2(b.x, b.y);
    }
  }
  if (tid < HD) hbuf[tid] = h0g[d * HD + tid];   // buffer 0
  float c = 0.0f;
  if (tid >= 256) c = c0g[d * HD + (tid - 256)];
  __syncthreads();

  int t = d ? (TT - 1) : 0;
  const int tstep = d ? -1 : 1;
  for (int it = 0; it < TT; ++it, t += tstep) {
    const float* Pt = g_P + ((size_t)d * TT + t) * NG;
    float pa = Pt[r0];
    float pb = Pt[r1];
    const float* hc = hbuf + (it & 1) * HD;

    float a0 = 0.f, b0 = 0.f, a1 = 0.f, b1 = 0.f;   // 4 chains for ILP
#pragma unroll
    for (int j = 0; j < NWv / 4; ++j) {             // 48 iters, 4 k-elems each
      const float4 hv = *reinterpret_cast<const float4*>(hc + j * 4);
      a0 = fmamix_lo(w0[2 * j],     hv.x, a0);
      a0 = fmamix_hi(w0[2 * j],     hv.y, a0);
      b0 = fmamix_lo(w0[2 * j + 1], hv.z, b0);
      b0 = fmamix_hi(w0[2 * j + 1], hv.w, b0);
      a1 = fmamix_lo(w1[2 * j],     hv.x, a1);
      a1 = fmamix_hi(w1[2 * j],     hv.y, a1);
      b1 = fmamix_lo(w1[2 * j + 1], hv.z, b1);
      b1 = fmamix_hi(w1[2 * j + 1], hv.w, b1);
    }
#pragma unroll
    for (int j = 0; j < NLv / 4; ++j) {             // 16 iters: LDS weight tails
      const float4 hv = *reinterpret_cast<const float4*>(hc + NWv + j * 4);
      const uint2 wa = *reinterpret_cast<const uint2*>(wlu + r0 * LSTRU + j * 2);
      const uint2 wb = *reinterpret_cast<const uint2*>(wlu + r1 * LSTRU + j * 2);
      a0 = fmamix_lo(wa.x, hv.x, a0);
      a0 = fmamix_hi(wa.x, hv.y, a0);
      b0 = fmamix_lo(wa.y, hv.z, b0);
      b0 = fmamix_hi(wa.y, hv.w, b0);
      a1 = fmamix_lo(wb.x, hv.x, a1);
      a1 = fmamix_hi(wb.x, hv.y, a1);
      b1 = fmamix_lo(wb.y, hv.z, b1);
      b1 = fmamix_hi(wb.y, hv.w, b1);
    }
    const float acc0 = (a0 + b0) + pa;
    const float acc1 = (a1 + b1) + pb;

    float sf = 0.f, so = 0.f;
    if (tid < 256) {
      aTerm[tid] = fsigmoid(acc0) * ftanh(acc1);    // i-gate, g-gate
    } else {
      sf = fsigmoid(acc0);                          // f-gate
      so = fsigmoid(acc1);                          // o-gate
    }
    __syncthreads();
    if (tid >= 256) {
      const int u = tid - 256;
      c = sf * c + aTerm[u];
      const float hh = so * ftanh(c);
      g_HS[((size_t)d * TT + t) * HD + u] = hh;
      hbuf[((it & 1) ^ 1) * HD + u] = hh;           // f32, no quantization
    }
    __syncthreads();
  }
}

// ---------------- K3: feats = [hf;hb] @ Wlin^T + blin (pure f32) ----------------
__global__ __launch_bounds__(256) void k_feats(
    const float* __restrict__ Wlin, const float* __restrict__ blin)
{
  const int gid = blockIdx.x * 256 + threadIdx.x;
  if (gid >= TT * NC) return;
  const int t = gid / NC, cc = gid - t * NC;
  const float* hf = g_HS + (size_t)t * HD;
  const float* hb = g_HS + ((size_t)TT + t) * HD;
  const float* wr = Wlin + cc * 512;
  float acc = blin[cc];
  for (int j = 0; j < HD; j += 4) {
    const float4 w = *reinterpret_cast<const float4*>(wr + j);
    acc += w.x * hf[j] + w.y * hf[j + 1] + w.z * hf[j + 2] + w.w * hf[j + 3];
  }
  for (int j = 0; j < HD; j += 4) {
    const float4 w = *reinterpret_cast<const float4*>(wr + 256 + j);
    acc += w.x * hb[j] + w.y * hb[j + 1] + w.z * hb[j + 2] + w.w * hb[j + 3];
  }
  g_FE[gid] = acc;
}

// ---------------- K4: Viterbi + backtrace (single wave); f32 in/out ----------------
__global__ __launch_bounds__(64) void k_vit(
    const float* __restrict__ trans, float* __restrict__ out)
{
  const int lane = threadIdx.x;
  const bool act = lane < NC;
  __shared__ unsigned char bp[TT][NC];
  float Trow[NC];
#pragma unroll
  for (int i = 0; i < NC; ++i) Trow[i] = act ? trans[lane * NC + i] : NEGV;
  float fv[NC];
#pragma unroll
  for (int i = 0; i < NC; ++i) fv[i] = (i == 10) ? 0.0f : NEGV;  // START=10

  float featN = act ? g_FE[lane] : 0.0f;
  for (int t = 0; t < TT; ++t) {
    const float feat = featN;
    if (t + 1 < TT) featN = act ? g_FE[(t + 1) * NC + lane] : 0.0f;
    float best = fv[0] + Trow[0]; int bi = 0;
#pragma unroll
    for (int i = 1; i < NC; ++i) {
      const float s = fv[i] + Trow[i];
      if (s > best) { best = s; bi = i; }   // strict > == jnp first-max tiebreak
    }
    if (act) bp[t][lane] = (unsigned char)bi;
    const float nf = best + feat;
#pragma unroll
    for (int i = 0; i < NC; ++i) fv[i] = __shfl(nf, i);
  }
  // terminal = fv + transitions[STOP=11] (row 11)
  const float term = act ? (fv[lane] + trans[11 * NC + lane]) : -3.0e38f;
  float tv[NC];
#pragma unroll
  for (int i = 0; i < NC; ++i) tv[i] = __shfl(term, i);
  if (lane == 0) {
    float bs = tv[0]; int bt = 0;
#pragma unroll
    for (int i = 1; i < NC; ++i) if (tv[i] > bs) { bs = tv[i]; bt = i; }
    out[0] = bs;                             // f32 path_score
    int tag = bt;
    for (int t = TT - 1; t >= 0; --t) {
      out[1 + t] = (float)tag;               // path tags as f32
      tag = bp[t][tag];
    }
  }
}

extern "C" void kernel_launch(void* const* d_in, const int* in_sizes, int n_in,
                              void* d_out, int out_size, void* d_ws, size_t ws_size,
                              hipStream_t stream) {
  const int*   sent = (const int*)d_in[0];
  const float* emb  = (const float*)d_in[1];
  const float* WihF = (const float*)d_in[2];
  const float* WhhF = (const float*)d_in[3];
  const float* bihF = (const float*)d_in[4];
  const float* bhhF = (const float*)d_in[5];
  const float* WihB = (const float*)d_in[6];
  const float* WhhB = (const float*)d_in[7];
  const float* bihB = (const float*)d_in[8];
  const float* bhhB = (const float*)d_in[9];
  const float* Wlin = (const float*)d_in[10];
  const float* blin = (const float*)d_in[11];
  const float* h0g  = (const float*)d_in[12];
  const float* c0g  = (const float*)d_in[13];
  const float* trans= (const float*)d_in[14];
  (void)d_ws; (void)ws_size; (void)in_sizes; (void)n_in; (void)out_size;

  k_input<<<dim3(2 * (TT / 16)), dim3(256), 0, stream>>>(
      sent, emb, WihF, bihF, bhhF, WihB, bihB, bhhB);

  k_rec<<<dim3(2), dim3(512), 0, stream>>>(WhhF, WhhB, h0g, c0g);

  k_feats<<<dim3((TT * NC + 255) / 256), dim3(256), 0, stream>>>(Wlin, blin);

  k_vit<<<dim3(1), dim3(64), 0, stream>>>(trans, (float*)d_out);
}